// Round 12
// baseline (93.733 us; speedup 1.0000x reference)
//
#include <hip/hip_runtime.h>

#define NBINS 2304                 // rebased: bin = (float_bits(d)>>18) - BINBASE
#define BINBASE 2048               // bin 0 <-> d ~ 5.4e-19; d<=4 -> bin <= 2113
#define ACC_OFF (3 * NBINS)        // word offset of per-layer n^2 accumulators in ws

typedef float    f4v __attribute__((ext_vector_type(4)));
typedef _Float16 h4v __attribute__((ext_vector_type(4)));

// ---- ts block: 16K t-elems + 16K s-elems (P positions x C channels) of one
// batch image. Every thread owns 16 channels x 4 consecutive positions. t,s
// retained in registers as f16 while f32 norms reduce through LDS; then
// register-only d histogram (no global re-read).
//
// Hard-won constraints (do not violate):
//  - DO NOT restructure the load loop (r5/r6: explicit pipelines collapsed MLP
//    or spilled to scratch).
//  - DO NOT fuse finalize behind a ticket (r7: acq_rel = +140us cache-maint
//    stalls; r9/r10 relaxed tests polluted by VGPR collapse).
//  - launch_bounds waves-arg >= 4 flips the compiler into pressure-limited
//    scheduling and spills th/sh (r3/r5/r9/r10: VGPR 36/52/40/48, scratch
//    WRITE visible, 1.5-2.9x slower). KEEP (256,3); VGPR must stay ~84, no
//    scratch traffic.
template<int C, int HWSHIFT, int PSHIFT, int LAYER>
__device__ __forceinline__ void ts_block(
    const float* __restrict__ t, const float* __restrict__ s,
    int lb, unsigned int* __restrict__ ws_u,
    unsigned int* cnt_sh, float* ov_sh, float* inv_sh)
{
    const int HW  = 1 << HWSHIFT;
    const int P   = 1 << PSHIFT;        // positions per block: 256/128/64
    const int NPQ = P >> 2;             // position-quads per wave: 64/32/16
    const int G   = 1024 >> PSHIFT;     // norm partials per position: 4/8/16
    const int tid = threadIdx.x;
    const int w   = tid >> 6;
    const int l   = tid & 63;
    const int pq  = l & (NPQ - 1);      // which position-quad
    const int cs  = l >> (PSHIFT - 2);  // channel sub-group within wave

    const int p0 = lb << PSHIFT;        // first flat position (never straddles b)
    const int b  = p0 >> HWSHIFT;
    const int q  = p0 & (HW - 1);
    const int c0 = w * (C / 4) + cs * 16;
    const size_t base = ((size_t)(b * C + c0) << HWSHIFT) + q + 4 * pq;

    const float* tp = t + base;
    const float* sp = s + base;

    // ---- zero histogram up-front: hides under the in-flight global loads ----
    #pragma unroll
    for (int i = tid; i < NBINS / 4; i += 256)
        ((uint4*)cnt_sh)[i] = make_uint4(0u, 0u, 0u, 0u);

    // ---- pass 1: batched loads (8 float4 in flight), f32 norm accum, f16 retain ----
    h4v th[16], sh[16];
    f4v accT = {0.f,0.f,0.f,0.f}, accS = {0.f,0.f,0.f,0.f};

    #pragma unroll
    for (int k0 = 0; k0 < 16; k0 += 4) {
        f4v tt[4], ss[4];
        #pragma unroll
        for (int u = 0; u < 4; ++u) {
            const size_t o = (size_t)(k0 + u) << HWSHIFT;
            tt[u] = *(const f4v*)(tp + o);
            ss[u] = *(const f4v*)(sp + o);
        }
        #pragma unroll
        for (int u = 0; u < 4; ++u) {
            accT += tt[u] * tt[u];
            accS += ss[u] * ss[u];
            th[k0+u] = (h4v){(_Float16)tt[u].x, (_Float16)tt[u].y,
                             (_Float16)tt[u].z, (_Float16)tt[u].w};
            sh[k0+u] = (h4v){(_Float16)ss[u].x, (_Float16)ss[u].y,
                             (_Float16)ss[u].z, (_Float16)ss[u].w};
        }
    }

    // cross-wave/lane-group norm combine via dedicated ov_sh buffer
    float* ovT = ov_sh;                 // [G][P] = 1024 floats
    float* ovS = ov_sh + 1024;          // 1024 floats
    const int g = (w * (64 / NPQ)) + cs;        // partial group id, 0..G-1
    ((f4v*)ovT)[g * NPQ + pq] = accT;           // linearizes to ovT[g*P + pos]
    ((f4v*)ovS)[g * NPQ + pq] = accS;
    __syncthreads();

    if (tid < P) {
        float nT = 0.f, nS = 0.f;
        #pragma unroll
        for (int gg = 0; gg < G; ++gg) { nT += ovT[gg * P + tid]; nS += ovS[gg * P + tid]; }
        inv_sh[tid]     = 1.0f / fmaxf(sqrtf(nT), 1e-12f);
        inv_sh[P + tid] = 1.0f / fmaxf(sqrtf(nS), 1e-12f);
    }
    __syncthreads();

    // ---- pass 2 (registers only): d = (t*invT - s*invS)^2, count histogram ----
    __builtin_amdgcn_s_setprio(1);      // win VALU issue vs co-resident n-waves
    f4v iT = ((const f4v*)inv_sh)[pq];
    f4v iS = ((const f4v*)(inv_sh + P))[pq];
    #pragma unroll
    for (int k = 0; k < 16; ++k) {
        f4v tv = {(float)th[k].x, (float)th[k].y, (float)th[k].z, (float)th[k].w};
        f4v sv = {(float)sh[k].x, (float)sh[k].y, (float)sh[k].z, (float)sh[k].w};
        f4v a  = tv * iT - sv * iS;
        f4v d  = a * a;
        int b0 = min(max((int)(__float_as_uint(d.x) >> 18) - BINBASE, 0), NBINS - 1);
        int b1 = min(max((int)(__float_as_uint(d.y) >> 18) - BINBASE, 0), NBINS - 1);
        int b2 = min(max((int)(__float_as_uint(d.z) >> 18) - BINBASE, 0), NBINS - 1);
        int b3 = min(max((int)(__float_as_uint(d.w) >> 18) - BINBASE, 0), NBINS - 1);
        atomicAdd(&cnt_sh[b0], 1u);
        atomicAdd(&cnt_sh[b1], 1u);
        atomicAdd(&cnt_sh[b2], 1u);
        atomicAdd(&cnt_sh[b3], 1u);
    }
    __syncthreads();

    // ---- flush nonzero bins to global per-layer histogram ----
    unsigned int* gc = ws_u + LAYER * NBINS;
    #pragma unroll
    for (int i = tid; i < NBINS; i += 256) {
        unsigned c = cnt_sh[i];
        if (c) atomicAdd(&gc[i], c);
    }
    __builtin_amdgcn_s_setprio(0);
}

// ---- n block: barrier-free streaming sum of squares over 128 KB (8192 f4).
// No barriers: these waves keep the memory pipe fed while co-resident ts
// blocks sit in reduce/histogram phases. ----
__device__ __forceinline__ void n_block(
    const float* __restrict__ n, int layer, int nb, float* __restrict__ ws_f)
{
    const f4v* p = (const f4v*)n + ((size_t)nb << 13) + threadIdx.x;
    float a = 0.f;
    #pragma unroll 8
    for (int i = 0; i < 32; ++i) {
        f4v v = __builtin_nontemporal_load(p + (size_t)i * 256);
        a += v.x*v.x + v.y*v.y + v.z*v.z + v.w*v.w;
    }
    #pragma unroll
    for (int o = 32; o > 0; o >>= 1) a += __shfl_down(a, o, 64);
    if ((threadIdx.x & 63) == 0) atomicAdd(&ws_f[ACC_OFF + layer], a);
}

// Grid: 2688 blocks, interleaved 2 ts : 1 n (bid%3==2 -> n).
// ts tiles (idx = g*2 + r): 256 (layer2) + 512 (layer1) + 1024 (layer0) = 1792.
// n  tiles (idx = g):       128 (n2) + 256 (n1) + 512 (n0) = 896.
__global__ __launch_bounds__(256, 3) void stfpm_hist(
    const float* __restrict__ t0, const float* __restrict__ s0, const float* __restrict__ n0,
    const float* __restrict__ t1, const float* __restrict__ s1, const float* __restrict__ n1,
    const float* __restrict__ t2, const float* __restrict__ s2, const float* __restrict__ n2,
    unsigned int* __restrict__ ws_u, float* __restrict__ ws_f)
{
    __shared__ __align__(16) unsigned int cnt_sh[NBINS];  // 9.2 KB
    __shared__ __align__(16) float ov_sh[2048];           // 8 KB norm overlay
    __shared__ __align__(16) float inv_sh[512];           // 2 KB
    const int bid = blockIdx.x;
    const int g   = bid / 3;
    const int r   = bid - g * 3;
    if (r == 2) {
        if (g < 128)      n_block(n2, 2, g,       ws_f);
        else if (g < 384) n_block(n1, 1, g - 128, ws_f);
        else              n_block(n0, 0, g - 384, ws_f);
        return;
    }
    const int ts = g * 2 + r;
    if (ts < 256)
        ts_block<256, 10, 6, 2>(t2, s2, ts,       ws_u, cnt_sh, ov_sh, inv_sh);
    else if (ts < 768)
        ts_block<128, 12, 7, 1>(t1, s1, ts - 256, ws_u, cnt_sh, ov_sh, inv_sh);
    else
        ts_block<64,  14, 8, 0>(t0, s0, ts - 768, ws_u, cnt_sh, ov_sh, inv_sh);
}

__device__ __forceinline__ float bin_lo(int b) {
    return __uint_as_float((unsigned)(b + BINBASE) << 18);
}
__device__ __forceinline__ float bin_mid(int b) {
    return 0.5f * (bin_lo(b) + bin_lo(b + 1));
}

// Single block: per layer, scan counts from the top; full bins above the
// boundary contribute cnt * bin-midpoint; boundary bin uses the uniform-
// within-bin model for its top-j elements. Adds mean(n^2); writes the scalar.
__global__ __launch_bounds__(256) void stfpm_finalize(
    const unsigned int* __restrict__ ws_u, const float* __restrict__ ws_f,
    float* __restrict__ out)
{
    __shared__ unsigned int cchunk[256];
    __shared__ float        schunk[256];
    const int tid = threadIdx.x;

    const int   targets[3] = {16778, 8389, 4195};  // cnt = N-1-floor(0.999(N-1))
    const float Ns[3]      = {16777216.f, 8388608.f, 4194304.f};
    const int   CHUNK = NBINS / 256;  // 9

    float total = 0.f;  // thread 0 only
    for (int layer = 0; layer < 3; ++layer) {
        const unsigned int* gc = ws_u + layer * NBINS;
        unsigned int c = 0; float sv = 0.f;
        const int b0 = tid * CHUNK;
        for (int i = 0; i < CHUNK; ++i) {
            unsigned cc = gc[b0 + i];
            c += cc;
            if (cc) sv += (float)cc * bin_mid(b0 + i);
        }
        __syncthreads();
        cchunk[tid] = c; schunk[tid] = sv;
        __syncthreads();
        if (tid == 0) {
            const int target = targets[layer];
            long long cum = 0; float sAbove = 0.f;
            int ch = 255;
            while (ch >= 0 && cum + (long long)cchunk[ch] < target) {
                cum += cchunk[ch]; sAbove += schunk[ch]; --ch;
            }
            int bin = ch * CHUNK + CHUNK - 1;
            while (bin >= ch * CHUNK && cum + (long long)gc[bin] < target) {
                unsigned cc = gc[bin];
                cum += cc; sAbove += (float)cc * bin_mid(bin); --bin;
            }
            unsigned cb = gc[bin];          // boundary bin count (>=1)
            int j = target - (int)cum;      // elements taken from boundary bin
            float lo = bin_lo(bin), hi = bin_lo(bin + 1);
            float wd = hi - lo;
            float f  = (float)j / (float)cb;
            float topmean = hi - f * wd * 0.5f;  // mean of top-j under uniform model
            topmean = fminf(fmaxf(topmean, lo), hi);
            float hard   = (sAbove + topmean * (float)j) / (float)target;
            float n2mean = ws_f[ACC_OFF + layer] / Ns[layer];
            total += hard + n2mean;
        }
        __syncthreads();
    }
    if (tid == 0) out[0] = total;
}

extern "C" void kernel_launch(void* const* d_in, const int* in_sizes, int n_in,
                              void* d_out, int out_size, void* d_ws, size_t ws_size,
                              hipStream_t stream)
{
    const float* t0 = (const float*)d_in[0];
    const float* s0 = (const float*)d_in[1];
    const float* n0 = (const float*)d_in[2];
    const float* t1 = (const float*)d_in[3];
    const float* s1 = (const float*)d_in[4];
    const float* n1 = (const float*)d_in[5];
    const float* t2 = (const float*)d_in[6];
    const float* s2 = (const float*)d_in[7];
    const float* n2 = (const float*)d_in[8];

    // zero per-layer histograms + accumulators (ws is NOT re-poisoned between replays)
    hipMemsetAsync(d_ws, 0, (size_t)(ACC_OFF + 8) * 4, stream);

    stfpm_hist<<<2688, 256, 0, stream>>>(t0, s0, n0, t1, s1, n1, t2, s2, n2,
                                         (unsigned int*)d_ws, (float*)d_ws);
    stfpm_finalize<<<1, 256, 0, stream>>>((const unsigned int*)d_ws,
                                          (const float*)d_ws, (float*)d_out);
}